// Round 12
// baseline (68723.932 us; speedup 1.0000x reference)
//
#include <hip/hip_runtime.h>
#include <math.h>
#include <stdint.h>

// ---------------- workspace layout (float32 indices) ----------------
// [0, 12288)            xg   [2 dir][6 vocab][1024 rows]
// [12288, 14336)        mailbox A (fast, sc0):  [2 dir][2 slot][256] of 8B (value,stamp)
// [14336, 16384)        mailbox B (safe, agent): same layout
// [16384, 16400)        election: cnt[8], winner, done, pad
// [20480, 20992)        stateH [2][256]
// [20992, 21504)        stateC [2][256]
// [21504, 1070080)      hist  [2 dir][2048 t][256]
// [1070080, 1070144)    ce partials [16 blk][4 wg]
// [1070144, 1070208)    ent partials [16 blk][4 wg]
static constexpr int XG_OFF   = 0;
static constexpr int MBA_OFF  = 12288;
static constexpr int MBB_OFF  = 14336;
static constexpr int ELEC_OFF = 16384;
static constexpr int SH_OFF   = 20480;
static constexpr int SC_OFF   = 20992;
static constexpr int HIST_OFF = 21504;
static constexpr int HIST_D   = 524288;   // per-dir floats (2048*256)
static constexpr int CEP_OFF  = 1070080;
static constexpr int ENTP_OFF = 1070144;

// d_out layout (float32): [0,32768) sampled idx; 32768 ce; 32769 ent;
// [32770,33282) h (fwd then bwd); [33282,33794) c
static constexpr int OUT_CE = 32768;
static constexpr int OUT_H  = 32770;
static constexpr int OUT_C  = 33282;

// ---------------- fast-path 8B ops (sc0: L1-bypass; same-XCD L2 meeting point) ----
__device__ __forceinline__ void st_sc0(unsigned long long* p, unsigned long long v) {
  asm volatile("global_store_dwordx2 %0, %1, off sc0" :: "v"(p), "v"(v) : "memory");
}
__device__ __forceinline__ unsigned long long ld_sc0(const unsigned long long* p) {
  unsigned long long r;
  asm volatile("global_load_dwordx2 %0, %1, off sc0\n\ts_waitcnt vmcnt(0)"
               : "=&v"(r) : "v"(p) : "memory");
  return r;
}

// ---------------- exact JAX threefry2x32 (20 rounds) ----------------
__device__ __forceinline__ uint32_t rotl32(uint32_t v, int n) {
  return (v << n) | (v >> (32 - n));
}
__device__ __forceinline__ void tf2x32(uint32_t k0, uint32_t k1,
                                       uint32_t x0, uint32_t x1,
                                       uint32_t& y0, uint32_t& y1) {
  const uint32_t k2 = k0 ^ k1 ^ 0x1BD11BDAu;
  x0 += k0; x1 += k1;
  x0 += x1; x1 = rotl32(x1, 13); x1 ^= x0;
  x0 += x1; x1 = rotl32(x1, 15); x1 ^= x0;
  x0 += x1; x1 = rotl32(x1, 26); x1 ^= x0;
  x0 += x1; x1 = rotl32(x1, 6);  x1 ^= x0;
  x0 += k1; x1 += k2 + 1u;
  x0 += x1; x1 = rotl32(x1, 17); x1 ^= x0;
  x0 += x1; x1 = rotl32(x1, 29); x1 ^= x0;
  x0 += x1; x1 = rotl32(x1, 16); x1 ^= x0;
  x0 += x1; x1 = rotl32(x1, 24); x1 ^= x0;
  x0 += k2; x1 += k0 + 2u;
  x0 += x1; x1 = rotl32(x1, 13); x1 ^= x0;
  x0 += x1; x1 = rotl32(x1, 15); x1 ^= x0;
  x0 += x1; x1 = rotl32(x1, 26); x1 ^= x0;
  x0 += x1; x1 = rotl32(x1, 6);  x1 ^= x0;
  x0 += k0; x1 += k1 + 3u;
  x0 += x1; x1 = rotl32(x1, 17); x1 ^= x0;
  x0 += x1; x1 = rotl32(x1, 29); x1 ^= x0;
  x0 += x1; x1 = rotl32(x1, 16); x1 ^= x0;
  x0 += x1; x1 = rotl32(x1, 24); x1 ^= x0;
  x0 += k1; x1 += k2 + 4u;
  x0 += x1; x1 = rotl32(x1, 13); x1 ^= x0;
  x0 += x1; x1 = rotl32(x1, 15); x1 ^= x0;
  x0 += x1; x1 = rotl32(x1, 26); x1 ^= x0;
  x0 += x1; x1 = rotl32(x1, 6);  x1 ^= x0;
  x0 += k2; x1 += k0 + 5u;
  y0 = x0; y1 = x1;
}

// gumbel = -log(-log(uniform(bits))), matching JAX's f32 rounding steps
__device__ __forceinline__ float gumbel_from_bits(uint32_t bits) {
  float f = __uint_as_float(0x3f800000u | (bits >> 9)) - 1.0f;
  const float tiny = __uint_as_float(0x00800000u);  // 2^-126
  float u = fmaxf(tiny, f + tiny);
  float l1 = (float)log((double)u);
  return -(float)log(-(double)l1);
}

// ---------------- xg precompute: emb[v] @ Wih.T + bih + bhh ----------------
__global__ void k_xg(const float* __restrict__ emb,
                     const float* __restrict__ WihF, const float* __restrict__ bihF,
                     const float* __restrict__ bhhF,
                     const float* __restrict__ WihB, const float* __restrict__ bihB,
                     const float* __restrict__ bhhB,
                     float* __restrict__ ws) {
  __shared__ float se[1536];
  const int tid = threadIdx.x;
  for (int i = tid; i < 1536; i += 256) se[i] = emb[i];
  __syncthreads();
  const int gid = blockIdx.x * 256 + tid;  // 0..2047
  const int d = gid >> 10, r = gid & 1023;
  const float* Wih = d ? WihB : WihF;
  const float* bih = d ? bihB : bihF;
  const float* bhh = d ? bhhB : bhhF;
  float acc[6] = {0.f, 0.f, 0.f, 0.f, 0.f, 0.f};
  const float4* wr = (const float4*)(Wih + r * 256);
  for (int c = 0; c < 64; c++) {
    float4 wv = wr[c];
#pragma unroll
    for (int v = 0; v < 6; v++) {
      const float* ev = &se[v * 256 + 4 * c];
      acc[v] += wv.x * ev[0] + wv.y * ev[1] + wv.z * ev[2] + wv.w * ev[3];
    }
  }
  const float bsum = bih[r] + bhh[r];
#pragma unroll
  for (int v = 0; v < 6; v++) ws[XG_OFF + d * 6144 + v * 1024 + r] = acc[v] + bsum;
}

// ---------------- election counter reset ----------------
__global__ void k_zero(float* __restrict__ ws) {
  if (threadIdx.x < 16) ((int*)(ws + ELEC_OFF))[threadIdx.x] = 0;
}

// ---------------- chain kernel: one block (2048 steps), both directions ----------------
// 128 WGs x 256 thr launched; first XCD to assemble 16 WGs wins; winners take
// roles: d=role>>3, k=role&7. WG (d,k) owns elems E=[32k,32k+32).
// Lane (w,q,p): elems eA=32k+8w+2q, eB=eA+1, ALL 4 gate types; 8 rows x 16 cols
// of Whh as pinned scalars. Exchange: dual-publish POSTED stores (agent B +
// sc0 A), NO vmcnt drain anywhere on the critical path; producers (p<2) never
// poll; lanes p>=2 poll exactly one remote elem (bounded sc0 probe + agent
// fallback). Barrier = lgkmcnt(0)+s_barrier only (no store-ack drain).
// Losing WGs spin on FMA junk until a done flag -> keeps DPM clocks boosted.
__global__ __launch_bounds__(256, 1)
void k_chain(const int* __restrict__ arc, const float* __restrict__ h0,
             const float* __restrict__ c0, const float* __restrict__ WhhF,
             const float* __restrict__ WhhB, float* __restrict__ ws,
             float* __restrict__ out, int b) {
  const int tid = threadIdx.x;
  __shared__ int role_s;
  __shared__ float xg_l[768];      // [6 sym][32 elem][4 gate] for own slice
  __shared__ int arc_s[2048];
  __shared__ float h_s[2][320];    // double-buffered, 16 chunks x 20 (padded)

  // --- election: first XCD to assemble 16 WGs wins (agent atomics only) ---
  if (tid == 0) {
    int xcc;
    asm volatile("s_getreg_b32 %0, hwreg(HW_REG_XCC_ID)" : "=s"(xcc));
    xcc &= 7;
    int* cnt = (int*)(ws + ELEC_OFF);
    int* winner = cnt + 8;
    int pos = __hip_atomic_fetch_add(&cnt[xcc], 1, __ATOMIC_RELAXED,
                                     __HIP_MEMORY_SCOPE_AGENT);
    if (pos == 15) {
      int expected = 0;
      __hip_atomic_compare_exchange_strong(winner, &expected, xcc + 1,
          __ATOMIC_RELAXED, __ATOMIC_RELAXED, __HIP_MEMORY_SCOPE_AGENT);
    }
    int wv;
    do {
      wv = __hip_atomic_load(winner, __ATOMIC_RELAXED, __HIP_MEMORY_SCOPE_AGENT);
    } while (wv == 0);
    role_s = (pos < 16 && wv == xcc + 1) ? pos : -1;
  }
  __syncthreads();
  const int role = role_s;
  if (role < 0) {
    // --- spinner: keep the chip busy so DPM holds boost clocks ---
    int* done = (int*)(ws + ELEC_OFF) + 9;
    float x = (float)tid + 1.5f;
    for (;;) {
#pragma unroll
      for (int i = 0; i < 512; i++) x = __builtin_fmaf(x, 1.0000001f, 1e-7f);
      asm volatile("" : "+v"(x));
      if (__hip_atomic_load(done, __ATOMIC_RELAXED, __HIP_MEMORY_SCOPE_AGENT) != 0)
        break;
    }
    return;
  }

  const int d = role >> 3;
  const int k = role & 7;
  const int w = tid >> 6;
  const int lane = tid & 63;
  const int q = lane >> 4, p = lane & 15;

  const float* Whh = d ? WhhB : WhhF;
  // xg slice: xg_l[sym*128 + el*4 + g] = xg[d][sym][g*256 + 32k + el]
  for (int i = tid; i < 768; i += 256) {
    const int sym = i >> 7, r = i & 127, el = r >> 2, g = r & 3;
    xg_l[i] = ws[XG_OFF + d * 6144 + sym * 1024 + g * 256 + 32 * k + el];
  }
  {
    const int* ab = arc + b * 2048;
    for (int i = tid; i < 2048; i += 256) arc_s[i] = ab[i];
  }
  // weights: row i -> gate (i>>1), elem eA + (i&1); 16 cols [16p,16p+16)
  const int eA = 32 * k + 8 * w + 2 * q;
  const int elA = 8 * w + 2 * q;
  float Wr[8][16];
#pragma unroll
  for (int i = 0; i < 8; i++) {
    const int R = 256 * (i >> 1) + eA + (i & 1);
    const float4* rp = (const float4*)(Whh + R * 256 + 16 * p);
#pragma unroll
    for (int j = 0; j < 4; j++) {
      const float4 v = rp[j];
      Wr[i][4 * j + 0] = v.x;
      Wr[i][4 * j + 1] = v.y;
      Wr[i][4 * j + 2] = v.z;
      Wr[i][4 * j + 3] = v.w;
    }
  }
#pragma unroll
  for (int i = 0; i < 8; i++)
#pragma unroll
    for (int c = 0; c < 16; c++)
      asm volatile("" : "+v"(Wr[i][c]));
  // initial state: lane reads its 16 h columns directly; c for its 2 elems
  const float* hprev = (b == 0) ? (h0 + d * 256) : (ws + SH_OFF + d * 256);
  float4 hw[4];
#pragma unroll
  for (int j = 0; j < 4; j++) hw[j] = ((const float4*)(hprev + 16 * p))[j];
  float cA = (b == 0) ? c0[d * 256 + eA] : ws[SC_OFF + d * 256 + eA];
  float cB = (b == 0) ? c0[d * 256 + eA + 1] : ws[SC_OFF + d * 256 + eA + 1];
  float hA = 0.f, hB = 0.f;
  __syncthreads();  // staging done

  unsigned long long* mbA = (unsigned long long*)(ws + MBA_OFF);
  unsigned long long* mbB = (unsigned long long*)(ws + MBB_OFF);
  const unsigned stampBase = (unsigned)b * 2048u;
  float* histD = ws + HIST_OFF + d * HIST_D;
  const bool producer = (p < 2);
  // poll assignment: lanes p>=2 (224 of them) each poll one remote elem
  int pollE = -1;
  if (p >= 2) {
    const int pi = (4 * w + q) * 14 + (p - 2);  // 0..223
    pollE = pi + (pi >= 32 * k ? 32 : 0);       // skip own 32 elems
  }
  int lim = 24, fails = 0;  // bounded fast-path probes

  for (int t = 0; t < 2048; t++) {
    // ---- matvec: 8 rows x 16 cols per lane ----
    float acc[8];
#pragma unroll
    for (int i = 0; i < 8; i++) {
      float a;
      a  = Wr[i][0]  * hw[0].x;
      a += Wr[i][1]  * hw[0].y;
      a += Wr[i][2]  * hw[0].z;
      a += Wr[i][3]  * hw[0].w;
      a += Wr[i][4]  * hw[1].x;
      a += Wr[i][5]  * hw[1].y;
      a += Wr[i][6]  * hw[1].z;
      a += Wr[i][7]  * hw[1].w;
      a += Wr[i][8]  * hw[2].x;
      a += Wr[i][9]  * hw[2].y;
      a += Wr[i][10] * hw[2].z;
      a += Wr[i][11] * hw[2].w;
      a += Wr[i][12] * hw[3].x;
      a += Wr[i][13] * hw[3].y;
      a += Wr[i][14] * hw[3].z;
      a += Wr[i][15] * hw[3].w;
      acc[i] = a;
    }
    // 16-lane allreduce
#pragma unroll
    for (int i = 0; i < 8; i++) {
      float v = acc[i];
      v += __shfl_xor(v, 1, 16);
      v += __shfl_xor(v, 2, 16);
      v += __shfl_xor(v, 4, 16);
      v += __shfl_xor(v, 8, 16);
      acc[i] = v;
    }
    // ---- in-register pointwise for the lane's 2 elems ----
    const int sym = arc_s[d ? (2047 - t) : t];
    const float4 xgA = *(const float4*)&xg_l[sym * 128 + elA * 4];
    const float4 xgB = *(const float4*)&xg_l[sym * 128 + elA * 4 + 4];
    {
      const float gi = acc[0] + xgA.x;
      const float gf = acc[2] + xgA.y;
      const float gg = acc[4] + xgA.z;
      const float go = acc[6] + xgA.w;
      const float I = 1.0f / (1.0f + expf(-gi));
      const float F = 1.0f / (1.0f + expf(-gf));
      const float G = tanhf(gg);
      const float O = 1.0f / (1.0f + expf(-go));
      cA = F * cA + I * G;
      hA = O * tanhf(cA);
    }
    {
      const float gi = acc[1] + xgB.x;
      const float gf = acc[3] + xgB.y;
      const float gg = acc[5] + xgB.z;
      const float go = acc[7] + xgB.w;
      const float I = 1.0f / (1.0f + expf(-gi));
      const float F = 1.0f / (1.0f + expf(-gf));
      const float G = tanhf(gg);
      const float O = 1.0f / (1.0f + expf(-go));
      cB = F * cB + I * G;
      hB = O * tanhf(cB);
    }
    const unsigned S = stampBase + (unsigned)t + 1u;
    const int mbo = (d * 2 + (t & 1)) * 256;
    unsigned long long* mbAp = mbA + mbo;
    unsigned long long* mbBp = mbB + mbo;
    const int np = (t + 1) & 1;
    // ---- publish: POSTED stores only, no drain ----
    if (producer) {
      const int e = eA + p;
      const float hv = p ? hB : hA;
      const unsigned long long pk = (unsigned long long)__float_as_uint(hv) |
                                    ((unsigned long long)S << 32);
      __hip_atomic_store(&mbBp[e], pk, __ATOMIC_RELAXED, __HIP_MEMORY_SCOPE_AGENT);
      st_sc0(&mbAp[e], pk);
      histD[t * 256 + e] = hv;
      h_s[np][(e >> 4) * 20 + (e & 15)] = hv;
    }
    if (t == 2047) break;
    // ---- consume: bounded sc0 probe, then agent fallback (p>=2 lanes only) ----
    if (pollE >= 0) {
      unsigned long long v = 0;
      bool got = false;
      for (int it = 0; it < lim; ++it) {
        unsigned long long f = ld_sc0(&mbAp[pollE]);
        if ((unsigned)(f >> 32) == S) { v = f; got = true; break; }
      }
      if (!got) {
        if (++fails >= 4) lim = 0;  // fast path broken: stop probing
        do {
          v = __hip_atomic_load(&mbBp[pollE], __ATOMIC_RELAXED,
                                __HIP_MEMORY_SCOPE_AGENT);
        } while ((unsigned)(v >> 32) != S);
      }
      h_s[np][(pollE >> 4) * 20 + (pollE & 15)] = __uint_as_float((unsigned)v);
    }
    // ---- barrier: LDS visibility only (no vmcnt drain) ----
    asm volatile("s_waitcnt lgkmcnt(0)" ::: "memory");
    __builtin_amdgcn_s_barrier();
    __builtin_amdgcn_sched_barrier(0);
    {
      const float4* hp = (const float4*)&h_s[np][20 * p];
#pragma unroll
      for (int j = 0; j < 4; j++) hw[j] = hp[j];
    }
  }

  if (producer) {
    const int e = eA + p;
    ws[SH_OFF + d * 256 + e] = p ? hB : hA;
    ws[SC_OFF + d * 256 + e] = p ? cB : cA;
    if (b == 15) {
      out[OUT_H + d * 256 + e] = p ? hB : hA;
      out[OUT_C + d * 256 + e] = p ? cB : cA;
    }
  }
  if (role == 0 && tid == 0)
    __hip_atomic_store(((int*)(ws + ELEC_OFF)) + 9, 1, __ATOMIC_RELAXED,
                       __HIP_MEMORY_SCOPE_AGENT);
}

// ---------------- sampler: one block's FC + gumbel-argmax + ce/ent ----------------
__global__ void k_sampler(const float* __restrict__ fcW, const float* __restrict__ fcb,
                          float* __restrict__ ws, float* __restrict__ out, int b) {
  const int tid = threadIdx.x;
  __shared__ float sW[5 * 512];
  __shared__ float sb[5];
  __shared__ float red[256];
  for (int i = tid; i < 2560; i += 256) sW[i] = fcW[i];
  if (tid < 5) sb[tid] = fcb[tid];
  __syncthreads();
  // split chain, jax_threefry_partitionable=True:
  // key_{i+1} = tf(key_i,(0,0)); sub_i = tf(key_i,(0,1))
  uint32_t s0 = 0u, s1 = 0u;
  {
    uint32_t k0 = 0u, k1 = 42u;
    for (int i = 0; i <= b; i++) {
      uint32_t n0, n1, t0, t1;
      tf2x32(k0, k1, 0u, 0u, n0, n1);
      tf2x32(k0, k1, 0u, 1u, t0, t1);
      s0 = t0; s1 = t1;
      k0 = n0; k1 = n1;
    }
  }
  const int pp = blockIdx.x * 256 + tid;  // 0..1023
  const float* histF = ws + HIST_OFF;
  const float* histB = ws + HIST_OFF + HIST_D;
  float dotL[5] = {0.f, 0.f, 0.f, 0.f, 0.f};
  float dotH[5] = {0.f, 0.f, 0.f, 0.f, 0.f};
  const float4* hfL = (const float4*)(histF + pp * 256);
  const float4* hbL = (const float4*)(histB + (2047 - pp) * 256);
  const float4* hfH = (const float4*)(histF + (pp + 1024) * 256);
  const float4* hbH = (const float4*)(histB + (1023 - pp) * 256);
  for (int c = 0; c < 64; c++) {
    float4 a = hfL[c], bb = hbL[c], e = hfH[c], f = hbH[c];
#pragma unroll
    for (int j = 0; j < 5; j++) {
      const float* wr = &sW[j * 512 + 4 * c];
      dotL[j] += a.x * wr[0] + a.y * wr[1] + a.z * wr[2] + a.w * wr[3];
      dotL[j] += bb.x * wr[256] + bb.y * wr[257] + bb.z * wr[258] + bb.w * wr[259];
      dotH[j] += e.x * wr[0] + e.y * wr[1] + e.z * wr[2] + e.w * wr[3];
      dotH[j] += f.x * wr[256] + f.y * wr[257] + f.z * wr[258] + f.w * wr[259];
    }
  }
  // partitionable random_bits (32b): bits(n) = y0^y1 of tf(sub,(0,n)), n=5t+j
  uint32_t bl[5], bh[5];
#pragma unroll
  for (int j = 0; j < 5; j++) {
    uint32_t y0, y1;
    tf2x32(s0, s1, 0u, (uint32_t)(5 * pp + j), y0, y1);
    bl[j] = y0 ^ y1;
    tf2x32(s0, s1, 0u, (uint32_t)(5 * (pp + 1024) + j), y0, y1);
    bh[j] = y0 ^ y1;
  }
  const float OPT = (float)(1.1 / 2.5);
  float ce_acc = 0.f, ent_acc = 0.f;
#pragma unroll
  for (int half = 0; half < 2; half++) {
    const int t = half ? (pp + 1024) : pp;
    float l[5];
#pragma unroll
    for (int j = 0; j < 5; j++) {
      float dv = half ? dotH[j] : dotL[j];
      l[j] = OPT * tanhf((dv + sb[j]) / 5.0f);
    }
    int idx = 0;
    float best;
    {
      uint32_t b0 = half ? bh[0] : bl[0];
      best = gumbel_from_bits(b0) + l[0];
    }
#pragma unroll
    for (int j = 1; j < 5; j++) {
      uint32_t bj = half ? bh[j] : bl[j];
      float v = gumbel_from_bits(bj) + l[j];
      if (v > best) { best = v; idx = j; }
    }
    out[b * 2048 + t] = (float)idx;
    float m = l[0];
#pragma unroll
    for (int j = 1; j < 5; j++) m = fmaxf(m, l[j]);
    float ssum = 0.f;
#pragma unroll
    for (int j = 0; j < 5; j++) ssum += expf(l[j] - m);
    float lse = logf(ssum);
    float lpidx = 0.f;
#pragma unroll
    for (int j = 0; j < 5; j++) {
      float lp = (l[j] - m) - lse;
      ent_acc -= lp * expf(lp);
      lpidx = (j == idx) ? lp : lpidx;
    }
    ce_acc -= lpidx;
  }
  red[tid] = ce_acc; __syncthreads();
  for (int s = 128; s > 0; s >>= 1) {
    if (tid < s) red[tid] += red[tid + s];
    __syncthreads();
  }
  if (tid == 0) ws[CEP_OFF + b * 4 + blockIdx.x] = red[0];
  __syncthreads();
  red[tid] = ent_acc; __syncthreads();
  for (int s = 128; s > 0; s >>= 1) {
    if (tid < s) red[tid] += red[tid + s];
    __syncthreads();
  }
  if (tid == 0) ws[ENTP_OFF + b * 4 + blockIdx.x] = red[0];
}

// ---------------- final reduce ----------------
__global__ void k_final(const float* __restrict__ ws, float* __restrict__ out) {
  if (threadIdx.x == 0 && blockIdx.x == 0) {
    float ce = 0.f, ent = 0.f;
    for (int b = 0; b < 16; b++) {
      float cb = 0.f, eb = 0.f;
      for (int j = 0; j < 4; j++) {
        cb += ws[CEP_OFF + b * 4 + j];
        eb += ws[ENTP_OFF + b * 4 + j];
      }
      ce += cb / 2048.0f;
      ent += eb / 10240.0f;
    }
    out[OUT_CE] = ce;
    out[OUT_CE + 1] = ent;
  }
}

extern "C" void kernel_launch(void* const* d_in, const int* in_sizes, int n_in,
                              void* d_out, int out_size, void* d_ws, size_t ws_size,
                              hipStream_t stream) {
  (void)in_sizes; (void)n_in; (void)out_size; (void)ws_size;
  const int* arc = (const int*)d_in[0];
  const float* h0 = (const float*)d_in[1];
  const float* c0 = (const float*)d_in[2];
  const float* emb = (const float*)d_in[3];
  const float* WihF = (const float*)d_in[4];
  const float* WhhF = (const float*)d_in[5];
  const float* bihF = (const float*)d_in[6];
  const float* bhhF = (const float*)d_in[7];
  const float* WihB = (const float*)d_in[8];
  const float* WhhB = (const float*)d_in[9];
  const float* bihB = (const float*)d_in[10];
  const float* bhhB = (const float*)d_in[11];
  const float* fcW = (const float*)d_in[12];
  const float* fcb = (const float*)d_in[13];
  float* out = (float*)d_out;
  float* ws = (float*)d_ws;

  hipLaunchKernelGGL(k_xg, dim3(8), dim3(256), 0, stream,
                     emb, WihF, bihF, bhhF, WihB, bihB, bhhB, ws);
  for (int b = 0; b < 16; b++) {
    hipLaunchKernelGGL(k_zero, dim3(1), dim3(64), 0, stream, ws);
    hipLaunchKernelGGL(k_chain, dim3(128), dim3(256), 0, stream,
                       arc, h0, c0, WhhF, WhhB, ws, out, b);
    hipLaunchKernelGGL(k_sampler, dim3(4), dim3(256), 0, stream,
                       fcW, fcb, ws, out, b);
  }
  hipLaunchKernelGGL(k_final, dim3(1), dim3(64), 0, stream, ws, out);
}

// Round 13
// 61943.500 us; speedup vs baseline: 1.1095x; 1.1095x over previous
//
#include <hip/hip_runtime.h>
#include <math.h>
#include <stdint.h>

// ---------------- workspace layout (float32 indices) ----------------
// [0, 12288)            xg   [2 dir][6 vocab][1024 rows]
// [12288, 14336)        mailbox A (fast, sc0):  [2 dir][2 slot][256] of 8B (value,stamp)
// [14336, 16384)        mailbox B (safe, agent): same layout
// [16384, 16400)        election: cnt[8], winner, pad
// [20480, 20992)        stateH [2][256]
// [20992, 21504)        stateC [2][256]
// [21504, 1070080)      hist  [2 dir][2048 t][256]
// [1070080, 1070144)    ce partials [16 blk][4 wg]
// [1070144, 1070208)    ent partials [16 blk][4 wg]
static constexpr int XG_OFF   = 0;
static constexpr int MBA_OFF  = 12288;
static constexpr int MBB_OFF  = 14336;
static constexpr int ELEC_OFF = 16384;
static constexpr int SH_OFF   = 20480;
static constexpr int SC_OFF   = 20992;
static constexpr int HIST_OFF = 21504;
static constexpr int HIST_D   = 524288;   // per-dir floats (2048*256)
static constexpr int CEP_OFF  = 1070080;
static constexpr int ENTP_OFF = 1070144;

// d_out layout (float32): [0,32768) sampled idx; 32768 ce; 32769 ent;
// [32770,33282) h (fwd then bwd); [33282,33794) c
static constexpr int OUT_CE = 32768;
static constexpr int OUT_H  = 32770;
static constexpr int OUT_C  = 33282;

typedef __attribute__((ext_vector_type(4))) float f32x4;

// ---------------- fast-path 8B ops (sc0: L1-bypass; same-XCD L2 meeting point) ----
__device__ __forceinline__ void st_sc0(unsigned long long* p, unsigned long long v) {
  asm volatile("global_store_dwordx2 %0, %1, off sc0" :: "v"(p), "v"(v) : "memory");
}
__device__ __forceinline__ unsigned long long ld_sc0(const unsigned long long* p) {
  unsigned long long r;
  asm volatile("global_load_dwordx2 %0, %1, off sc0\n\ts_waitcnt vmcnt(0)"
               : "=&v"(r) : "v"(p) : "memory");
  return r;
}

// ---------------- exact JAX threefry2x32 (20 rounds) ----------------
__device__ __forceinline__ uint32_t rotl32(uint32_t v, int n) {
  return (v << n) | (v >> (32 - n));
}
__device__ __forceinline__ void tf2x32(uint32_t k0, uint32_t k1,
                                       uint32_t x0, uint32_t x1,
                                       uint32_t& y0, uint32_t& y1) {
  const uint32_t k2 = k0 ^ k1 ^ 0x1BD11BDAu;
  x0 += k0; x1 += k1;
  x0 += x1; x1 = rotl32(x1, 13); x1 ^= x0;
  x0 += x1; x1 = rotl32(x1, 15); x1 ^= x0;
  x0 += x1; x1 = rotl32(x1, 26); x1 ^= x0;
  x0 += x1; x1 = rotl32(x1, 6);  x1 ^= x0;
  x0 += k1; x1 += k2 + 1u;
  x0 += x1; x1 = rotl32(x1, 17); x1 ^= x0;
  x0 += x1; x1 = rotl32(x1, 29); x1 ^= x0;
  x0 += x1; x1 = rotl32(x1, 16); x1 ^= x0;
  x0 += x1; x1 = rotl32(x1, 24); x1 ^= x0;
  x0 += k2; x1 += k0 + 2u;
  x0 += x1; x1 = rotl32(x1, 13); x1 ^= x0;
  x0 += x1; x1 = rotl32(x1, 15); x1 ^= x0;
  x0 += x1; x1 = rotl32(x1, 26); x1 ^= x0;
  x0 += x1; x1 = rotl32(x1, 6);  x1 ^= x0;
  x0 += k0; x1 += k1 + 3u;
  x0 += x1; x1 = rotl32(x1, 17); x1 ^= x0;
  x0 += x1; x1 = rotl32(x1, 29); x1 ^= x0;
  x0 += x1; x1 = rotl32(x1, 16); x1 ^= x0;
  x0 += x1; x1 = rotl32(x1, 24); x1 ^= x0;
  x0 += k1; x1 += k2 + 4u;
  x0 += x1; x1 = rotl32(x1, 13); x1 ^= x0;
  x0 += x1; x1 = rotl32(x1, 15); x1 ^= x0;
  x0 += x1; x1 = rotl32(x1, 26); x1 ^= x0;
  x0 += x1; x1 = rotl32(x1, 6);  x1 ^= x0;
  x0 += k2; x1 += k0 + 5u;
  y0 = x0; y1 = x1;
}

// gumbel = -log(-log(uniform(bits))), matching JAX's f32 rounding steps
__device__ __forceinline__ float gumbel_from_bits(uint32_t bits) {
  float f = __uint_as_float(0x3f800000u | (bits >> 9)) - 1.0f;
  const float tiny = __uint_as_float(0x00800000u);  // 2^-126
  float u = fmaxf(tiny, f + tiny);
  float l1 = (float)log((double)u);
  return -(float)log(-(double)l1);
}

// ---------------- xg precompute: emb[v] @ Wih.T + bih + bhh ----------------
__global__ void k_xg(const float* __restrict__ emb,
                     const float* __restrict__ WihF, const float* __restrict__ bihF,
                     const float* __restrict__ bhhF,
                     const float* __restrict__ WihB, const float* __restrict__ bihB,
                     const float* __restrict__ bhhB,
                     float* __restrict__ ws) {
  __shared__ float se[1536];
  const int tid = threadIdx.x;
  for (int i = tid; i < 1536; i += 256) se[i] = emb[i];
  __syncthreads();
  const int gid = blockIdx.x * 256 + tid;  // 0..2047
  const int d = gid >> 10, r = gid & 1023;
  const float* Wih = d ? WihB : WihF;
  const float* bih = d ? bihB : bihF;
  const float* bhh = d ? bhhB : bhhF;
  float acc[6] = {0.f, 0.f, 0.f, 0.f, 0.f, 0.f};
  const float4* wr = (const float4*)(Wih + r * 256);
  for (int c = 0; c < 64; c++) {
    float4 wv = wr[c];
#pragma unroll
    for (int v = 0; v < 6; v++) {
      const float* ev = &se[v * 256 + 4 * c];
      acc[v] += wv.x * ev[0] + wv.y * ev[1] + wv.z * ev[2] + wv.w * ev[3];
    }
  }
  const float bsum = bih[r] + bhh[r];
#pragma unroll
  for (int v = 0; v < 6; v++) ws[XG_OFF + d * 6144 + v * 1024 + r] = acc[v] + bsum;
}

// ---------------- election counter reset ----------------
__global__ void k_zero(float* __restrict__ ws) {
  if (threadIdx.x < 16) ((int*)(ws + ELEC_OFF))[threadIdx.x] = 0;
}

// ---------------- chain kernel: one block (2048 steps), both directions ----------------
// 128 WGs x 256 thr launched; first XCD to assemble 16 WGs wins; winners take
// roles: d=role>>3, k=role&7. WG (d,k) owns elems E=[32k,32k+32).
// Lane (w,q,p): elems eA=32k+8w+2q, eB=eA+1, ALL 4 gate types; 8 rows x 16 cols
// of Whh loaded via INLINE-ASM global_load_dwordx4 (results are opaque to the
// compiler -> cannot be rematerialized from Whh inside the loop) and kept in
// VGPRs under amdgpu_waves_per_eu(1,1) (512-VGPR budget; r11 ran VGPR=88 with
// per-step L2 reloads of all 128 weights on the critical path). Exchange:
// dual-publish (agent mailbox B = proven path; sc0 mailbox A = same-XCD L2 fast
// path, r9-verified via FETCH_SIZE collapse); bounded probe + agent fallback.
__global__ __launch_bounds__(256, 1) __attribute__((amdgpu_waves_per_eu(1, 1)))
void k_chain(const int* __restrict__ arc, const float* __restrict__ h0,
             const float* __restrict__ c0, const float* __restrict__ WhhF,
             const float* __restrict__ WhhB, float* __restrict__ ws,
             float* __restrict__ out, int b) {
  const int tid = threadIdx.x;
  __shared__ int role_s;
  __shared__ float xg_l[768];      // [6 sym][32 elem][4 gate] for own slice
  __shared__ int arc_s[2048];
  __shared__ float h_s[2][320];    // double-buffered, 16 chunks x 20 (padded)

  // --- election: first XCD to assemble 16 WGs wins (agent atomics only) ---
  if (tid == 0) {
    int xcc;
    asm volatile("s_getreg_b32 %0, hwreg(HW_REG_XCC_ID)" : "=s"(xcc));
    xcc &= 7;
    int* cnt = (int*)(ws + ELEC_OFF);
    int* winner = cnt + 8;
    int pos = __hip_atomic_fetch_add(&cnt[xcc], 1, __ATOMIC_RELAXED,
                                     __HIP_MEMORY_SCOPE_AGENT);
    if (pos == 15) {
      int expected = 0;
      __hip_atomic_compare_exchange_strong(winner, &expected, xcc + 1,
          __ATOMIC_RELAXED, __ATOMIC_RELAXED, __HIP_MEMORY_SCOPE_AGENT);
    }
    int wv;
    do {
      wv = __hip_atomic_load(winner, __ATOMIC_RELAXED, __HIP_MEMORY_SCOPE_AGENT);
    } while (wv == 0);
    role_s = (pos < 16 && wv == xcc + 1) ? pos : -1;
  }
  __syncthreads();
  const int role = role_s;
  if (role < 0) return;

  const int d = role >> 3;
  const int k = role & 7;
  const int w = tid >> 6;
  const int lane = tid & 63;
  const int q = lane >> 4, p = lane & 15;

  const float* Whh = d ? WhhB : WhhF;
  // xg slice: xg_l[sym*128 + el*4 + g] = xg[d][sym][g*256 + 32k + el]
  for (int i = tid; i < 768; i += 256) {
    const int sym = i >> 7, r = i & 127, el = r >> 2, g = r & 3;
    xg_l[i] = ws[XG_OFF + d * 6144 + sym * 1024 + g * 256 + 32 * k + el];
  }
  {
    const int* ab = arc + b * 2048;
    for (int i = tid; i < 2048; i += 256) arc_s[i] = ab[i];
  }
  // weights: row i -> gate (i>>1), elem eA + (i&1); 16 cols [16p,16p+16)
  // Loaded via asm so values CANNOT be rematerialized inside the step loop.
  const int eA = 32 * k + 8 * w + 2 * q;
  const int elA = 8 * w + 2 * q;
  f32x4 Wv[32];
#pragma unroll
  for (int i = 0; i < 8; i++) {
    const int R = 256 * (i >> 1) + eA + (i & 1);
    const float* rp = Whh + R * 256 + 16 * p;
#pragma unroll
    for (int j = 0; j < 4; j++) {
      asm volatile("global_load_dwordx4 %0, %1, off"
                   : "=v"(Wv[4 * i + j]) : "v"(rp + 4 * j));
    }
  }
  asm volatile("s_waitcnt vmcnt(0)" ::: "memory");
  // initial state: lane reads its 16 h columns directly; c for its 2 elems
  const float* hprev = (b == 0) ? (h0 + d * 256) : (ws + SH_OFF + d * 256);
  float4 hw[4];
#pragma unroll
  for (int j = 0; j < 4; j++) hw[j] = ((const float4*)(hprev + 16 * p))[j];
  float cA = (b == 0) ? c0[d * 256 + eA] : ws[SC_OFF + d * 256 + eA];
  float cB = (b == 0) ? c0[d * 256 + eA + 1] : ws[SC_OFF + d * 256 + eA + 1];
  float hA = 0.f, hB = 0.f;
  __syncthreads();  // staging done

  unsigned long long* mbA = (unsigned long long*)(ws + MBA_OFF);
  unsigned long long* mbB = (unsigned long long*)(ws + MBB_OFF);
  const unsigned stampBase = (unsigned)b * 2048u;
  float* histD = ws + HIST_OFF + d * HIST_D;
  const bool selfPoll = ((tid >> 5) == k);  // elem tid produced by this WG
  int lim = 24, fails = 0;                  // bounded fast-path probes

  for (int t = 0; t < 2048; t++) {
    // ---- matvec: 8 rows x 16 cols per lane (W register-resident) ----
    float acc[8];
#pragma unroll
    for (int i = 0; i < 8; i++) {
      float a;
      a  = Wv[4 * i + 0].x * hw[0].x;
      a += Wv[4 * i + 0].y * hw[0].y;
      a += Wv[4 * i + 0].z * hw[0].z;
      a += Wv[4 * i + 0].w * hw[0].w;
      a += Wv[4 * i + 1].x * hw[1].x;
      a += Wv[4 * i + 1].y * hw[1].y;
      a += Wv[4 * i + 1].z * hw[1].z;
      a += Wv[4 * i + 1].w * hw[1].w;
      a += Wv[4 * i + 2].x * hw[2].x;
      a += Wv[4 * i + 2].y * hw[2].y;
      a += Wv[4 * i + 2].z * hw[2].z;
      a += Wv[4 * i + 2].w * hw[2].w;
      a += Wv[4 * i + 3].x * hw[3].x;
      a += Wv[4 * i + 3].y * hw[3].y;
      a += Wv[4 * i + 3].z * hw[3].z;
      a += Wv[4 * i + 3].w * hw[3].w;
      acc[i] = a;
    }
    // 16-lane allreduce
#pragma unroll
    for (int i = 0; i < 8; i++) {
      float v = acc[i];
      v += __shfl_xor(v, 1, 16);
      v += __shfl_xor(v, 2, 16);
      v += __shfl_xor(v, 4, 16);
      v += __shfl_xor(v, 8, 16);
      acc[i] = v;
    }
    // ---- in-register pointwise for the lane's 2 elems ----
    const int sym = arc_s[d ? (2047 - t) : t];
    const float4 xgA = *(const float4*)&xg_l[sym * 128 + elA * 4];
    const float4 xgB = *(const float4*)&xg_l[sym * 128 + elA * 4 + 4];
    {
      const float gi = acc[0] + xgA.x;
      const float gf = acc[2] + xgA.y;
      const float gg = acc[4] + xgA.z;
      const float go = acc[6] + xgA.w;
      const float I = 1.0f / (1.0f + expf(-gi));
      const float F = 1.0f / (1.0f + expf(-gf));
      const float G = tanhf(gg);
      const float O = 1.0f / (1.0f + expf(-go));
      cA = F * cA + I * G;
      hA = O * tanhf(cA);
    }
    {
      const float gi = acc[1] + xgB.x;
      const float gf = acc[3] + xgB.y;
      const float gg = acc[5] + xgB.z;
      const float go = acc[7] + xgB.w;
      const float I = 1.0f / (1.0f + expf(-gi));
      const float F = 1.0f / (1.0f + expf(-gf));
      const float G = tanhf(gg);
      const float O = 1.0f / (1.0f + expf(-go));
      cB = F * cB + I * G;
      hB = O * tanhf(cB);
    }
    // ---- publish: agent (guaranteed) + sc0 (fast), then flush ----
    const unsigned S = stampBase + (unsigned)t + 1u;
    const int mbo = (d * 2 + (t & 1)) * 256;
    unsigned long long* mbAp = mbA + mbo;
    unsigned long long* mbBp = mbB + mbo;
    const int np = (t + 1) & 1;
    if (p < 2) {
      const int e = eA + p;
      const float hv = p ? hB : hA;
      const unsigned long long pk = (unsigned long long)__float_as_uint(hv) |
                                    ((unsigned long long)S << 32);
      __hip_atomic_store(&mbBp[e], pk, __ATOMIC_RELAXED, __HIP_MEMORY_SCOPE_AGENT);
      st_sc0(&mbAp[e], pk);
      histD[t * 256 + e] = hv;
      h_s[np][(e >> 4) * 20 + (e & 15)] = hv;
    }
    asm volatile("s_waitcnt vmcnt(0)" ::: "memory");  // publishes en route
    if (t == 2047) break;  // no poll after the last step
    // ---- consume: bounded sc0 probe, then proven agent poll ----
    {
      unsigned long long v = 0;
      bool got = false;
      for (int it = 0; it < lim; ++it) {
        unsigned long long f = selfPoll ? 0ull : ld_sc0(&mbAp[tid]);
        bool ok = selfPoll | ((unsigned)(f >> 32) == S);
        if (__all(ok)) { v = f; got = true; break; }
      }
      if (!got) {
        if (++fails >= 4) lim = 0;  // fast path broken: stop probing
        for (;;) {
          unsigned long long f = selfPoll ? 0ull :
              __hip_atomic_load(&mbBp[tid], __ATOMIC_RELAXED,
                                __HIP_MEMORY_SCOPE_AGENT);
          bool ok = selfPoll | ((unsigned)(f >> 32) == S);
          if (__all(ok)) { v = f; break; }
        }
      }
      if (!selfPoll)
        h_s[np][(tid >> 4) * 20 + (tid & 15)] = __uint_as_float((unsigned)v);
    }
    __syncthreads();  // h_s[np] complete
    {
      const float4* hp = (const float4*)&h_s[np][20 * p];
#pragma unroll
      for (int j = 0; j < 4; j++) hw[j] = hp[j];
    }
  }

  if (p < 2) {
    const int e = eA + p;
    ws[SH_OFF + d * 256 + e] = p ? hB : hA;
    ws[SC_OFF + d * 256 + e] = p ? cB : cA;
    if (b == 15) {
      out[OUT_H + d * 256 + e] = p ? hB : hA;
      out[OUT_C + d * 256 + e] = p ? cB : cA;
    }
  }
}

// ---------------- sampler: one block's FC + gumbel-argmax + ce/ent ----------------
__global__ void k_sampler(const float* __restrict__ fcW, const float* __restrict__ fcb,
                          float* __restrict__ ws, float* __restrict__ out, int b) {
  const int tid = threadIdx.x;
  __shared__ float sW[5 * 512];
  __shared__ float sb[5];
  __shared__ float red[256];
  for (int i = tid; i < 2560; i += 256) sW[i] = fcW[i];
  if (tid < 5) sb[tid] = fcb[tid];
  __syncthreads();
  // split chain, jax_threefry_partitionable=True:
  // key_{i+1} = tf(key_i,(0,0)); sub_i = tf(key_i,(0,1))
  uint32_t s0 = 0u, s1 = 0u;
  {
    uint32_t k0 = 0u, k1 = 42u;
    for (int i = 0; i <= b; i++) {
      uint32_t n0, n1, t0, t1;
      tf2x32(k0, k1, 0u, 0u, n0, n1);
      tf2x32(k0, k1, 0u, 1u, t0, t1);
      s0 = t0; s1 = t1;
      k0 = n0; k1 = n1;
    }
  }
  const int pp = blockIdx.x * 256 + tid;  // 0..1023
  const float* histF = ws + HIST_OFF;
  const float* histB = ws + HIST_OFF + HIST_D;
  float dotL[5] = {0.f, 0.f, 0.f, 0.f, 0.f};
  float dotH[5] = {0.f, 0.f, 0.f, 0.f, 0.f};
  const float4* hfL = (const float4*)(histF + pp * 256);
  const float4* hbL = (const float4*)(histB + (2047 - pp) * 256);
  const float4* hfH = (const float4*)(histF + (pp + 1024) * 256);
  const float4* hbH = (const float4*)(histB + (1023 - pp) * 256);
  for (int c = 0; c < 64; c++) {
    float4 a = hfL[c], bb = hbL[c], e = hfH[c], f = hbH[c];
#pragma unroll
    for (int j = 0; j < 5; j++) {
      const float* wr = &sW[j * 512 + 4 * c];
      dotL[j] += a.x * wr[0] + a.y * wr[1] + a.z * wr[2] + a.w * wr[3];
      dotL[j] += bb.x * wr[256] + bb.y * wr[257] + bb.z * wr[258] + bb.w * wr[259];
      dotH[j] += e.x * wr[0] + e.y * wr[1] + e.z * wr[2] + e.w * wr[3];
      dotH[j] += f.x * wr[256] + f.y * wr[257] + f.z * wr[258] + f.w * wr[259];
    }
  }
  // partitionable random_bits (32b): bits(n) = y0^y1 of tf(sub,(0,n)), n=5t+j
  uint32_t bl[5], bh[5];
#pragma unroll
  for (int j = 0; j < 5; j++) {
    uint32_t y0, y1;
    tf2x32(s0, s1, 0u, (uint32_t)(5 * pp + j), y0, y1);
    bl[j] = y0 ^ y1;
    tf2x32(s0, s1, 0u, (uint32_t)(5 * (pp + 1024) + j), y0, y1);
    bh[j] = y0 ^ y1;
  }
  const float OPT = (float)(1.1 / 2.5);
  float ce_acc = 0.f, ent_acc = 0.f;
#pragma unroll
  for (int half = 0; half < 2; half++) {
    const int t = half ? (pp + 1024) : pp;
    float l[5];
#pragma unroll
    for (int j = 0; j < 5; j++) {
      float dv = half ? dotH[j] : dotL[j];
      l[j] = OPT * tanhf((dv + sb[j]) / 5.0f);
    }
    int idx = 0;
    float best;
    {
      uint32_t b0 = half ? bh[0] : bl[0];
      best = gumbel_from_bits(b0) + l[0];
    }
#pragma unroll
    for (int j = 1; j < 5; j++) {
      uint32_t bj = half ? bh[j] : bl[j];
      float v = gumbel_from_bits(bj) + l[j];
      if (v > best) { best = v; idx = j; }
    }
    out[b * 2048 + t] = (float)idx;
    float m = l[0];
#pragma unroll
    for (int j = 1; j < 5; j++) m = fmaxf(m, l[j]);
    float ssum = 0.f;
#pragma unroll
    for (int j = 0; j < 5; j++) ssum += expf(l[j] - m);
    float lse = logf(ssum);
    float lpidx = 0.f;
#pragma unroll
    for (int j = 0; j < 5; j++) {
      float lp = (l[j] - m) - lse;
      ent_acc -= lp * expf(lp);
      lpidx = (j == idx) ? lp : lpidx;
    }
    ce_acc -= lpidx;
  }
  red[tid] = ce_acc; __syncthreads();
  for (int s = 128; s > 0; s >>= 1) {
    if (tid < s) red[tid] += red[tid + s];
    __syncthreads();
  }
  if (tid == 0) ws[CEP_OFF + b * 4 + blockIdx.x] = red[0];
  __syncthreads();
  red[tid] = ent_acc; __syncthreads();
  for (int s = 128; s > 0; s >>= 1) {
    if (tid < s) red[tid] += red[tid + s];
    __syncthreads();
  }
  if (tid == 0) ws[ENTP_OFF + b * 4 + blockIdx.x] = red[0];
}

// ---------------- final reduce ----------------
__global__ void k_final(const float* __restrict__ ws, float* __restrict__ out) {
  if (threadIdx.x == 0 && blockIdx.x == 0) {
    float ce = 0.f, ent = 0.f;
    for (int b = 0; b < 16; b++) {
      float cb = 0.f, eb = 0.f;
      for (int j = 0; j < 4; j++) {
        cb += ws[CEP_OFF + b * 4 + j];
        eb += ws[ENTP_OFF + b * 4 + j];
      }
      ce += cb / 2048.0f;
      ent += eb / 10240.0f;
    }
    out[OUT_CE] = ce;
    out[OUT_CE + 1] = ent;
  }
}

extern "C" void kernel_launch(void* const* d_in, const int* in_sizes, int n_in,
                              void* d_out, int out_size, void* d_ws, size_t ws_size,
                              hipStream_t stream) {
  (void)in_sizes; (void)n_in; (void)out_size; (void)ws_size;
  const int* arc = (const int*)d_in[0];
  const float* h0 = (const float*)d_in[1];
  const float* c0 = (const float*)d_in[2];
  const float* emb = (const float*)d_in[3];
  const float* WihF = (const float*)d_in[4];
  const float* WhhF = (const float*)d_in[5];
  const float* bihF = (const float*)d_in[6];
  const float* bhhF = (const float*)d_in[7];
  const float* WihB = (const float*)d_in[8];
  const float* WhhB = (const float*)d_in[9];
  const float* bihB = (const float*)d_in[10];
  const float* bhhB = (const float*)d_in[11];
  const float* fcW = (const float*)d_in[12];
  const float* fcb = (const float*)d_in[13];
  float* out = (float*)d_out;
  float* ws = (float*)d_ws;

  hipLaunchKernelGGL(k_xg, dim3(8), dim3(256), 0, stream,
                     emb, WihF, bihF, bhhF, WihB, bihB, bhhB, ws);
  for (int b = 0; b < 16; b++) {
    hipLaunchKernelGGL(k_zero, dim3(1), dim3(64), 0, stream, ws);
    hipLaunchKernelGGL(k_chain, dim3(128), dim3(256), 0, stream,
                       arc, h0, c0, WhhF, WhhB, ws, out, b);
    hipLaunchKernelGGL(k_sampler, dim3(4), dim3(256), 0, stream,
                       fcW, fcb, ws, out, b);
  }
  hipLaunchKernelGGL(k_final, dim3(1), dim3(64), 0, stream, ws, out);
}